// Round 8
// baseline (533.801 us; speedup 1.0000x reference)
//
#include <hip/hip_runtime.h>
#include <hip/hip_bf16.h>

typedef __attribute__((ext_vector_type(8))) short short8;
typedef __attribute__((ext_vector_type(4))) short s16x4;
typedef __attribute__((ext_vector_type(4))) float f32x4;
typedef unsigned short u16;

#define DEV __device__ __forceinline__
#define MFMA32(a, b, c) __builtin_amdgcn_mfma_f32_16x16x32_bf16(a, b, c, 0, 0, 0)
#define MFMA16(a, b, c) __builtin_amdgcn_mfma_f32_16x16x16bf16_1k(a, b, c, 0, 0, 0)
#define SBAR() asm volatile("s_barrier" ::: "memory")

DEV u16 f2b(float f) {
    __hip_bfloat16 h = __float2bfloat16(f);
    return __builtin_bit_cast(unsigned short, h);
}

DEV float max3f(float a, float b, float c) {
    float d;
    asm("v_max3_f32 %0, %1, %2, %3" : "=v"(d) : "v"(a), "v"(b), "v"(c));
    return d;
}

DEV void gl_lds16(const u16* g, u16* l) {
    __builtin_amdgcn_global_load_lds((const unsigned int*)g, (unsigned int*)l, 16, 0, 0);
}

// ---------------- cast x: fp32 -> bf16 ----------------
__global__ __launch_bounds__(256) void cast_bf16(const float* __restrict__ in, u16* __restrict__ out, int n) {
    int i = (blockIdx.x * 256 + threadIdx.x) * 4;
    if (i < n) {
        float4 v = *(const float4*)(in + i);
        ushort4 o;
        o.x = f2b(v.x); o.y = f2b(v.y); o.z = f2b(v.z); o.w = f2b(v.w);
        *(ushort4*)(out + i) = o;
    }
}

// ---------------- transpose + cast: W[R][C] fp32 -> Wt[C][R] bf16 ----------------
__global__ __launch_bounds__(256) void transpose_cast(const float* __restrict__ in, u16* __restrict__ out,
                                                      int R, int C) {
    __shared__ float t[32][33];
    int bx = blockIdx.x * 32;
    int by = blockIdx.y * 32;
    int tx = threadIdx.x, ty = threadIdx.y;  // (32, 8)
#pragma unroll
    for (int i = 0; i < 32; i += 8) t[ty + i][tx] = in[(size_t)(by + ty + i) * C + bx + tx];
    __syncthreads();
#pragma unroll
    for (int i = 0; i < 32; i += 8) out[(size_t)(bx + ty + i) * R + by + tx] = f2b(t[tx][ty + i]);
}

// ---------------- pack biases into one buffer ----------------
__global__ __launch_bounds__(256) void pack_bias(const float* __restrict__ bq, const float* __restrict__ bk,
                                                 const float* __restrict__ bv, const float* __restrict__ bo,
                                                 const float* __restrict__ b1, const float* __restrict__ b2,
                                                 float* __restrict__ out) {
    int i = blockIdx.x * 256 + threadIdx.x;
    if (i >= 9216) return;
    float v;
    if (i < 1024) v = bq[i];
    else if (i < 2048) v = bk[i - 1024];
    else if (i < 3072) v = bv[i - 2048];
    else if (i < 4096) v = bo[i - 3072];
    else if (i < 8192) v = b1[i - 4096];
    else v = b2[i - 8192];
    out[i] = v;
}

// ---------------- GEMM: C[M][N] = A[M][K] * Bt[N][K]^T + bias (+res), optional GELU ----------------
// m97 structure (proven best here): 128x128 tile, BK=32, 256 threads (4 waves, 2x2),
// global_load_lds width 16, 2 barriers per K-step, ~3 blocks/CU for implicit overlap.
template <bool GELU, bool BF16OUT, bool RESID>
__global__ __launch_bounds__(256) void gemm_bt(const u16* __restrict__ A, const u16* __restrict__ B,
                                               const float* __restrict__ bias, float* __restrict__ cf,
                                               u16* __restrict__ cb, const float* __restrict__ res,
                                               int M, int N, int K) {
    __shared__ __align__(16) u16 As[128 * 32];
    __shared__ __align__(16) u16 Bs[128 * 32];
    const int tid = threadIdx.x;
    const int wid = tid >> 6, lane = tid & 63;
    const int wr = wid >> 1, wc = wid & 1;
    const int m0 = blockIdx.x * 128, n0 = blockIdx.y * 128;
    const int r16 = lane & 15, g = lane >> 4;
    const int lrow = lane >> 2, lk = (lane & 3) * 8;

    f32x4 acc[4][4];
#pragma unroll
    for (int i = 0; i < 4; i++)
#pragma unroll
        for (int j = 0; j < 4; j++) acc[i][j] = (f32x4){0.f, 0.f, 0.f, 0.f};

    const u16* ga = A + (size_t)(m0 + wid * 32 + lrow) * K + lk;
    const u16* gb = B + (size_t)(n0 + wid * 32 + lrow) * K + lk;
    u16* lA0 = &As[(wid * 32) * 32];
    u16* lA1 = &As[(wid * 32 + 16) * 32];
    u16* lB0 = &Bs[(wid * 32) * 32];
    u16* lB1 = &Bs[(wid * 32 + 16) * 32];

    for (int kt = 0; kt < K; kt += 32) {
        gl_lds16(ga + kt, lA0);
        gl_lds16(ga + (size_t)16 * K + kt, lA1);
        gl_lds16(gb + kt, lB0);
        gl_lds16(gb + (size_t)16 * K + kt, lB1);
        __syncthreads();
        short8 af[4], bfr[4];
#pragma unroll
        for (int i = 0; i < 4; i++) af[i] = *(const short8*)&As[(wr * 64 + i * 16 + r16) * 32 + g * 8];
#pragma unroll
        for (int j = 0; j < 4; j++) bfr[j] = *(const short8*)&Bs[(wc * 64 + j * 16 + r16) * 32 + g * 8];
#pragma unroll
        for (int i = 0; i < 4; i++)
#pragma unroll
            for (int j = 0; j < 4; j++) acc[i][j] = MFMA32(af[i], bfr[j], acc[i][j]);
        __syncthreads();
    }

#pragma unroll
    for (int i = 0; i < 4; i++) {
#pragma unroll
        for (int j = 0; j < 4; j++) {
#pragma unroll
            for (int r = 0; r < 4; r++) {
                int row = m0 + wr * 64 + i * 16 + g * 4 + r;
                int col = n0 + wc * 64 + j * 16 + r16;
                float v = acc[i][j][r] + bias[col];
                if (RESID) v += res[(size_t)row * N + col];
                if (GELU) v = 0.5f * v * (1.0f + erff(v * 0.70710678118654752f));
                if (BF16OUT) cb[(size_t)row * N + col] = f2b(v);
                else cf[(size_t)row * N + col] = v;
            }
        }
    }
}

// ---------------- flash attention (swapped-QK^T, KBLK=64, async double-buffered K/V) ----------------
__global__ __launch_bounds__(256) void attn_kernel(const u16* __restrict__ qkv, const int* __restrict__ mask,
                                                   u16* __restrict__ ctx) {
    const int tid = threadIdx.x, wid = tid >> 6, lane = tid & 63;
    const int r16 = lane & 15, g = lane >> 4;
    const int h = blockIdx.y, b = blockIdx.z;
    const size_t baserow = (size_t)b * 2048;
    const int q0 = blockIdx.x * 64;

    __shared__ __align__(16) u16 Ks[2][64 * 64];
    __shared__ __align__(16) u16 Vs[2][64 * 64];
    __shared__ __align__(16) float mb_all[2048];

    const float SCALE = 0.18033688011112042f;   // 0.125 * log2(e)
    const float MNEG = -6.196328018e9f;         // -2^32 * log2(e)
    const s16x4 ONES = {(short)0x3F80, (short)0x3F80, (short)0x3F80, (short)0x3F80};

    short8 qf0, qf1;
    {
        const u16* qp = qkv + (baserow + q0 + wid * 16 + r16) * 3072 + h * 64 + g * 8;
        qf0 = *(const short8*)qp;
        qf1 = *(const short8*)(qp + 32);
    }

    const int L = lane;
    const int kchunk = (L & 7) ^ (L >> 3);
    const u16* kg0 = qkv + (baserow + wid * 16 + (L >> 3)) * 3072 + 1024 + h * 64 + kchunk * 8;
    const u16* kg1 = kg0 + (size_t)8 * 3072;
    const u16* vg0 = qkv + (baserow + wid * 16 + ((L & 31) >> 1)) * 3072 + 2048 + h * 64
                     + ((L >> 5) * 16 + (L & 1) * 8);
    const u16* vg1 = vg0 + 32;
    const unsigned vaddr = (unsigned)(unsigned long long)&Vs[0][0] + (unsigned)(r16 * 2 + g * 128);

    // mask bias for the whole sequence, once
    for (int i = tid; i < 2048; i += 256) mb_all[i] = mask[baserow + i] ? MNEG : 0.0f;

    // prologue: stage tile 0 into buf 0
    gl_lds16(kg0, &Ks[0][wid * 1024]);
    gl_lds16(kg1, &Ks[0][wid * 1024 + 512]);
    gl_lds16(vg0, &Vs[0][wid * 1024]);
    gl_lds16(vg1, &Vs[0][wid * 1024 + 512]);
    __syncthreads();    // drains tile-0 loads + mb writes

    f32x4 Ot[4];
#pragma unroll
    for (int dt = 0; dt < 4; dt++) Ot[dt] = (f32x4){0.f, 0.f, 0.f, 0.f};
    f32x4 Osum = (f32x4){0.f, 0.f, 0.f, 0.f};   // denominator via ones-column MFMA
    float mrun = -1e30f;

    for (int t = 0; t < 32; ++t) {
        const int cur = t & 1, nb = cur ^ 1;
        if (t < 31) {
            const size_t go = (size_t)(t + 1) * 64 * 3072;
            gl_lds16(kg0 + go, &Ks[nb][wid * 1024]);
            gl_lds16(kg1 + go, &Ks[nb][wid * 1024 + 512]);
            gl_lds16(vg0 + go, &Vs[nb][wid * 1024]);
            gl_lds16(vg1 + go, &Vs[nb][wid * 1024 + 512]);
            asm volatile("s_waitcnt vmcnt(4)" ::: "memory");   // tile t landed; t+1 in flight
        } else {
            asm volatile("s_waitcnt vmcnt(0)" ::: "memory");
        }
        SBAR();

        // S^T tiles: z[tt] = K_tile(tt) x Q  -> lane holds S[tt*16+4g+j][q=r16]
        f32x4 z[4];
        __builtin_amdgcn_s_setprio(1);
#pragma unroll
        for (int tt = 0; tt < 4; tt++) {
            const int row = tt * 16 + r16;
            const int swz = row & 7;
            short8 a0 = *(const short8*)&Ks[cur][row * 64 + ((g ^ swz) * 8)];
            short8 a1 = *(const short8*)&Ks[cur][row * 64 + (((4 + g) ^ swz) * 8)];
            f32x4 zz = (f32x4){0.f, 0.f, 0.f, 0.f};
            zz = MFMA32(a0, qf0, zz);
            zz = MFMA32(a1, qf1, zz);
            z[tt] = zz;
        }
        __builtin_amdgcn_s_setprio(0);

        f32x4 sv[4];
#pragma unroll
        for (int tt = 0; tt < 4; tt++) {
            f32x4 mbv = *(const f32x4*)&mb_all[t * 64 + tt * 16 + g * 4];
            sv[tt] = z[tt] * SCALE + mbv;
        }

        // row max via v_max3 tree + 2 cross-group shfls
        float m0 = max3f(sv[0][0], sv[0][1], sv[0][2]);
        float m1 = max3f(sv[0][3], sv[1][0], sv[1][1]);
        float m2 = max3f(sv[1][2], sv[1][3], sv[2][0]);
        float m3 = max3f(sv[2][1], sv[2][2], sv[2][3]);
        float m4 = max3f(sv[3][0], sv[3][1], sv[3][2]);
        float pmax = fmaxf(max3f(m0, m1, m2), max3f(m3, m4, sv[3][3]));
        pmax = fmaxf(pmax, __shfl_xor(pmax, 16));
        pmax = fmaxf(pmax, __shfl_xor(pmax, 32));

        // defer-max (THR = 11.5 in log2 domain ~= 8 nats)
        if (!__all(pmax - mrun <= 11.5f)) {
            float mnew = fmaxf(mrun, pmax);
            float alpha = exp2f(mrun - mnew);
            mrun = mnew;
            Osum *= alpha;
#pragma unroll
            for (int dt = 0; dt < 4; dt++) Ot[dt] *= alpha;
        }

        // p = 2^(s'-m), pack via v_cvt_pk_bf16_f32 (row-sum comes from ones-MFMA)
        s16x4 pb[4];
#pragma unroll
        for (int tt = 0; tt < 4; tt++) {
            f32x4 d = sv[tt] - mrun;
            float p0 = exp2f(d[0]), p1 = exp2f(d[1]), p2 = exp2f(d[2]), p3 = exp2f(d[3]);
            unsigned lo, hi;
            asm("v_cvt_pk_bf16_f32 %0, %1, %2" : "=v"(lo) : "v"(p0), "v"(p1));
            asm("v_cvt_pk_bf16_f32 %0, %1, %2" : "=v"(hi) : "v"(p2), "v"(p3));
            uint2 u; u.x = lo; u.y = hi;
            pb[tt] = __builtin_bit_cast(s16x4, u);
        }

        // PV: O^T[dt] += V^T_frag(tt,dt) x P_frag(tt); Osum += 1^T x P_frag(tt)
        s16x4 vf[4][4];
        const unsigned va_cur = vaddr + (unsigned)(cur * 8192);
#pragma unroll
        for (int tt = 0; tt < 4; tt++)
#pragma unroll
            for (int dt = 0; dt < 4; dt++)
                asm volatile("ds_read_b64_tr_b16 %0, %1"
                             : "=v"(vf[tt][dt])
                             : "v"(va_cur + (unsigned)((tt * 4 + dt) * 512)));
        asm volatile("s_waitcnt lgkmcnt(0)" ::: "memory");
        __builtin_amdgcn_sched_barrier(0);
        __builtin_amdgcn_s_setprio(1);
#pragma unroll
        for (int tt = 0; tt < 4; tt++) {
#pragma unroll
            for (int dt = 0; dt < 4; dt++) Ot[dt] = MFMA16(vf[tt][dt], pb[tt], Ot[dt]);
            Osum = MFMA16(ONES, pb[tt], Osum);
        }
        __builtin_amdgcn_s_setprio(0);
        SBAR();   // all reads of buf `cur` retired; next iter may overwrite it
    }

    const float rl = 1.0f / Osum[0];
    u16* cp = ctx + (baserow + q0 + wid * 16 + r16) * 1024 + h * 64 + g * 4;
#pragma unroll
    for (int dt = 0; dt < 4; dt++) {
        ushort4 o4;
        o4.x = f2b(Ot[dt][0] * rl);
        o4.y = f2b(Ot[dt][1] * rl);
        o4.z = f2b(Ot[dt][2] * rl);
        o4.w = f2b(Ot[dt][3] * rl);
        *(ushort4*)(cp + dt * 16) = o4;
    }
}

// ---------------- fused residual + layernorm (res optional) ----------------
__global__ __launch_bounds__(256) void ln_kernel(const float* __restrict__ a, const float* __restrict__ res,
                                                 const float* __restrict__ gamma, const float* __restrict__ beta,
                                                 float* __restrict__ outf, u16* __restrict__ outb) {
    const int row = blockIdx.x, tid = threadIdx.x;
    const size_t base = (size_t)row * 1024 + tid * 4;
    float4 va = *(const float4*)(a + base);
    float x0 = va.x, x1 = va.y, x2 = va.z, x3 = va.w;
    if (res) {
        float4 vr = *(const float4*)(res + base);
        x0 += vr.x; x1 += vr.y; x2 += vr.z; x3 += vr.w;
    }
    float s = x0 + x1 + x2 + x3;
    float ss = x0 * x0 + x1 * x1 + x2 * x2 + x3 * x3;
#pragma unroll
    for (int m = 1; m < 64; m <<= 1) { s += __shfl_xor(s, m, 64); ss += __shfl_xor(ss, m, 64); }
    __shared__ float red[8];
    if ((tid & 63) == 0) { red[tid >> 6] = s; red[4 + (tid >> 6)] = ss; }
    __syncthreads();
    s = red[0] + red[1] + red[2] + red[3];
    ss = red[4] + red[5] + red[6] + red[7];
    float mu = s * (1.0f / 1024.0f);
    float var = ss * (1.0f / 1024.0f) - mu * mu;
    float rstd = rsqrtf(var + 1e-5f);
    float4 g4 = *(const float4*)(gamma + tid * 4);
    float4 b4 = *(const float4*)(beta + tid * 4);
    float y0 = (x0 - mu) * rstd * g4.x + b4.x;
    float y1 = (x1 - mu) * rstd * g4.y + b4.y;
    float y2 = (x2 - mu) * rstd * g4.z + b4.z;
    float y3 = (x3 - mu) * rstd * g4.w + b4.w;
    *(float4*)(outf + base) = make_float4(y0, y1, y2, y3);
    if (outb) {
        ushort4 ob;
        ob.x = f2b(y0); ob.y = f2b(y1); ob.z = f2b(y2); ob.w = f2b(y3);
        *(ushort4*)(outb + base) = ob;
    }
}

extern "C" void kernel_launch(void* const* d_in, const int* in_sizes, int n_in, void* d_out, int out_size,
                              void* d_ws, size_t ws_size, hipStream_t stream) {
    const float* x = (const float*)d_in[0];
    const int* mask = (const int*)d_in[1];
    const float* Wq = (const float*)d_in[2];
    const float* bq = (const float*)d_in[3];
    const float* Wk = (const float*)d_in[4];
    const float* bk = (const float*)d_in[5];
    const float* Wv = (const float*)d_in[6];
    const float* bv = (const float*)d_in[7];
    const float* Wo = (const float*)d_in[8];
    const float* bo = (const float*)d_in[9];
    const float* ln1s = (const float*)d_in[10];
    const float* ln1b = (const float*)d_in[11];
    const float* W1 = (const float*)d_in[12];
    const float* b1 = (const float*)d_in[13];
    const float* W2 = (const float*)d_in[14];
    const float* b2 = (const float*)d_in[15];
    const float* ln2s = (const float*)d_in[16];
    const float* ln2b = (const float*)d_in[17];
    float* out = (float*)d_out;
    char* ws = (char*)d_ws;

    const size_t MB = 1024 * 1024;
    u16* XB = (u16*)(ws + 0);                 // x bf16 [8192][1024]
    u16* WTq = (u16*)(ws + 16 * MB);          // [Wq^T;Wk^T;Wv^T] = Bt[3072][1024]
    u16* WTk = WTq + 1024 * 1024;
    u16* WTv = WTk + 1024 * 1024;
    u16* WTo = WTv + 1024 * 1024;             // Wo^T [1024][1024]
    u16* WT1 = WTo + 1024 * 1024;             // W1^T [4096][1024]
    u16* WT2 = WT1 + 4096 * 1024;             // W2^T [1024][4096]
    float* BIAS = (float*)(ws + 40 * MB);
    u16* QKV = (u16*)(ws + 41 * MB);          // [8192][3072] bf16
    u16* CTX = (u16*)(ws + 0);                // [8192][1024] bf16 (reuse XB)
    float* ATT = (float*)(ws + 41 * MB);      // attn_out + x, fp32 (reuse QKV)
    float* Hbuf = (float*)(ws + 73 * MB);
    u16* HB = (u16*)(ws + 105 * MB);
    u16* MLP1 = (u16*)(ws + 121 * MB);        // [8192][4096] bf16
    float* MLP2 = (float*)(ws + 41 * MB);     // mlp2 + h, fp32 (reuse ATT)

    dim3 tb(32, 8);
    cast_bf16<<<8192, 256, 0, stream>>>(x, XB, 8192 * 1024);
    transpose_cast<<<dim3(32, 32), tb, 0, stream>>>(Wq, WTq, 1024, 1024);
    transpose_cast<<<dim3(32, 32), tb, 0, stream>>>(Wk, WTk, 1024, 1024);
    transpose_cast<<<dim3(32, 32), tb, 0, stream>>>(Wv, WTv, 1024, 1024);
    transpose_cast<<<dim3(32, 32), tb, 0, stream>>>(Wo, WTo, 1024, 1024);
    transpose_cast<<<dim3(128, 32), tb, 0, stream>>>(W1, WT1, 1024, 4096);
    transpose_cast<<<dim3(32, 128), tb, 0, stream>>>(W2, WT2, 4096, 1024);
    pack_bias<<<36, 256, 0, stream>>>(bq, bk, bv, bo, b1, b2, BIAS);

    // QKV projection: [8192][3072]
    gemm_bt<false, true, false><<<dim3(64, 24), 256, 0, stream>>>(XB, WTq, BIAS, nullptr, QKV, nullptr, 8192, 3072, 1024);
    attn_kernel<<<dim3(32, 16, 4), 256, 0, stream>>>(QKV, mask, CTX);
    // output projection + residual x (fp32 out)
    gemm_bt<false, false, true><<<dim3(64, 8), 256, 0, stream>>>(CTX, WTo, BIAS + 3072, ATT, nullptr, x, 8192, 1024, 1024);
    ln_kernel<<<8192, 256, 0, stream>>>(ATT, nullptr, ln1s, ln1b, Hbuf, HB);
    // mlp1 = gelu(h @ W1 + b1)
    gemm_bt<true, true, false><<<dim3(64, 32), 256, 0, stream>>>(HB, WT1, BIAS + 4096, nullptr, MLP1, nullptr, 8192, 4096, 1024);
    // mlp2 = mlp1 @ W2 + b2 + h
    gemm_bt<false, false, true><<<dim3(64, 8), 256, 0, stream>>>(MLP1, WT2, BIAS + 8192, MLP2, nullptr, Hbuf, 8192, 1024, 4096);
    ln_kernel<<<8192, 256, 0, stream>>>(MLP2, nullptr, ln2s, ln2b, out, nullptr);
}

// Round 9
// 519.400 us; speedup vs baseline: 1.0277x; 1.0277x over previous
//
#include <hip/hip_runtime.h>
#include <hip/hip_bf16.h>

typedef __attribute__((ext_vector_type(8))) short short8;
typedef __attribute__((ext_vector_type(4))) short s16x4;
typedef __attribute__((ext_vector_type(4))) float f32x4;
typedef unsigned short u16;

#define DEV __device__ __forceinline__
#define MFMA32(a, b, c) __builtin_amdgcn_mfma_f32_16x16x32_bf16(a, b, c, 0, 0, 0)
#define MFMA16(a, b, c) __builtin_amdgcn_mfma_f32_16x16x16bf16_1k(a, b, c, 0, 0, 0)

DEV u16 f2b(float f) {
    __hip_bfloat16 h = __float2bfloat16(f);
    return __builtin_bit_cast(unsigned short, h);
}

DEV float max3f(float a, float b, float c) {
    float d;
    asm("v_max3_f32 %0, %1, %2, %3" : "=v"(d) : "v"(a), "v"(b), "v"(c));
    return d;
}

DEV void gl_lds16(const u16* g, u16* l) {
    __builtin_amdgcn_global_load_lds((const unsigned int*)g, (unsigned int*)l, 16, 0, 0);
}

// ---------------- cast x: fp32 -> bf16 ----------------
__global__ __launch_bounds__(256) void cast_bf16(const float* __restrict__ in, u16* __restrict__ out, int n) {
    int i = (blockIdx.x * 256 + threadIdx.x) * 4;
    if (i < n) {
        float4 v = *(const float4*)(in + i);
        ushort4 o;
        o.x = f2b(v.x); o.y = f2b(v.y); o.z = f2b(v.z); o.w = f2b(v.w);
        *(ushort4*)(out + i) = o;
    }
}

// ---------------- transpose + cast: W[R][C] fp32 -> Wt[C][R] bf16 ----------------
__global__ __launch_bounds__(256) void transpose_cast(const float* __restrict__ in, u16* __restrict__ out,
                                                      int R, int C) {
    __shared__ float t[32][33];
    int bx = blockIdx.x * 32;
    int by = blockIdx.y * 32;
    int tx = threadIdx.x, ty = threadIdx.y;  // (32, 8)
#pragma unroll
    for (int i = 0; i < 32; i += 8) t[ty + i][tx] = in[(size_t)(by + ty + i) * C + bx + tx];
    __syncthreads();
#pragma unroll
    for (int i = 0; i < 32; i += 8) out[(size_t)(bx + ty + i) * R + by + tx] = f2b(t[tx][ty + i]);
}

// ---------------- pack biases into one buffer ----------------
__global__ __launch_bounds__(256) void pack_bias(const float* __restrict__ bq, const float* __restrict__ bk,
                                                 const float* __restrict__ bv, const float* __restrict__ bo,
                                                 const float* __restrict__ b1, const float* __restrict__ b2,
                                                 float* __restrict__ out) {
    int i = blockIdx.x * 256 + threadIdx.x;
    if (i >= 9216) return;
    float v;
    if (i < 1024) v = bq[i];
    else if (i < 2048) v = bk[i - 1024];
    else if (i < 3072) v = bv[i - 2048];
    else if (i < 4096) v = bo[i - 3072];
    else if (i < 8192) v = b1[i - 4096];
    else v = b2[i - 8192];
    out[i] = v;
}

// ---------------- GEMM: C[M][N] = A[M][K] * Bt[N][K]^T + bias (+res), optional GELU ----------------
// m97 structure (proven best here): 128x128 tile, BK=32, 256 threads (4 waves, 2x2),
// global_load_lds width 16, 2 barriers per K-step, ~3+ blocks/CU for implicit overlap.
template <bool GELU, bool BF16OUT, bool RESID>
__global__ __launch_bounds__(256) void gemm_bt(const u16* __restrict__ A, const u16* __restrict__ B,
                                               const float* __restrict__ bias, float* __restrict__ cf,
                                               u16* __restrict__ cb, const float* __restrict__ res,
                                               int M, int N, int K) {
    __shared__ __align__(16) u16 As[128 * 32];
    __shared__ __align__(16) u16 Bs[128 * 32];
    const int tid = threadIdx.x;
    const int wid = tid >> 6, lane = tid & 63;
    const int wr = wid >> 1, wc = wid & 1;
    const int m0 = blockIdx.x * 128, n0 = blockIdx.y * 128;
    const int r16 = lane & 15, g = lane >> 4;
    const int lrow = lane >> 2, lk = (lane & 3) * 8;

    f32x4 acc[4][4];
#pragma unroll
    for (int i = 0; i < 4; i++)
#pragma unroll
        for (int j = 0; j < 4; j++) acc[i][j] = (f32x4){0.f, 0.f, 0.f, 0.f};

    const u16* ga = A + (size_t)(m0 + wid * 32 + lrow) * K + lk;
    const u16* gb = B + (size_t)(n0 + wid * 32 + lrow) * K + lk;
    u16* lA0 = &As[(wid * 32) * 32];
    u16* lA1 = &As[(wid * 32 + 16) * 32];
    u16* lB0 = &Bs[(wid * 32) * 32];
    u16* lB1 = &Bs[(wid * 32 + 16) * 32];

    for (int kt = 0; kt < K; kt += 32) {
        gl_lds16(ga + kt, lA0);
        gl_lds16(ga + (size_t)16 * K + kt, lA1);
        gl_lds16(gb + kt, lB0);
        gl_lds16(gb + (size_t)16 * K + kt, lB1);
        __syncthreads();
        short8 af[4], bfr[4];
#pragma unroll
        for (int i = 0; i < 4; i++) af[i] = *(const short8*)&As[(wr * 64 + i * 16 + r16) * 32 + g * 8];
#pragma unroll
        for (int j = 0; j < 4; j++) bfr[j] = *(const short8*)&Bs[(wc * 64 + j * 16 + r16) * 32 + g * 8];
#pragma unroll
        for (int i = 0; i < 4; i++)
#pragma unroll
            for (int j = 0; j < 4; j++) acc[i][j] = MFMA32(af[i], bfr[j], acc[i][j]);
        __syncthreads();
    }

#pragma unroll
    for (int i = 0; i < 4; i++) {
#pragma unroll
        for (int j = 0; j < 4; j++) {
#pragma unroll
            for (int r = 0; r < 4; r++) {
                int row = m0 + wr * 64 + i * 16 + g * 4 + r;
                int col = n0 + wc * 64 + j * 16 + r16;
                float v = acc[i][j][r] + bias[col];
                if (RESID) v += res[(size_t)row * N + col];
                if (GELU) v = 0.5f * v * (1.0f + erff(v * 0.70710678118654752f));
                if (BF16OUT) cb[(size_t)row * N + col] = f2b(v);
                else cf[(size_t)row * N + col] = v;
            }
        }
    }
}

// ---------------- flash attention (swapped-QK^T, KBLK=64, mask fast-path) ----------------
__global__ __launch_bounds__(256) void attn_kernel(const u16* __restrict__ qkv, const int* __restrict__ mask,
                                                   u16* __restrict__ ctx) {
    const int tid = threadIdx.x, wid = tid >> 6, lane = tid & 63;
    const int r16 = lane & 15, g = lane >> 4;
    const int h = blockIdx.y, b = blockIdx.z;
    const size_t baserow = (size_t)b * 2048;
    const int q0 = blockIdx.x * 64;

    __shared__ __align__(16) u16 Ks[64 * 64];
    __shared__ __align__(16) u16 Vs[64 * 64];
    __shared__ unsigned tflags_sh;

    const float SCALE = 0.18033688011112042f;   // 0.125 * log2(e)
    const float MNEG = -6.196328018e9f;         // -2^32 * log2(e)
    const s16x4 ONES = {(short)0x3F80, (short)0x3F80, (short)0x3F80, (short)0x3F80};

    short8 qf0, qf1;
    {
        const u16* qp = qkv + (baserow + q0 + wid * 16 + r16) * 3072 + h * 64 + g * 8;
        qf0 = *(const short8*)qp;
        qf1 = *(const short8*)(qp + 32);
    }

    // per-tile has-mask bitmask (one u32 for all 32 tiles), computed once
    if (tid == 0) tflags_sh = 0;
    __syncthreads();
    for (int r = 0; r < 8; ++r) {
        int v = mask[baserow + r * 256 + tid];
        unsigned long long bal = __ballot(v != 0);
        if (bal != 0 && lane == 0) atomicOr(&tflags_sh, 1u << (r * 4 + wid));
    }

    const int L = lane;
    const int kchunk = (L & 7) ^ (L >> 3);
    const u16* kg0 = qkv + (baserow + wid * 16 + (L >> 3)) * 3072 + 1024 + h * 64 + kchunk * 8;
    const u16* kg1 = kg0 + (size_t)8 * 3072;
    u16* kl0 = &Ks[wid * 1024];
    u16* kl1 = &Ks[wid * 1024 + 512];
    const u16* vg0 = qkv + (baserow + wid * 16 + ((L & 31) >> 1)) * 3072 + 2048 + h * 64
                     + ((L >> 5) * 16 + (L & 1) * 8);
    const u16* vg1 = vg0 + 32;
    u16* vl0 = &Vs[wid * 1024];
    u16* vl1 = &Vs[wid * 1024 + 512];
    const unsigned vaddr = (unsigned)(unsigned long long)&Vs[0] + (unsigned)(r16 * 2 + g * 128);

    __syncthreads();            // tflags ready
    const unsigned tfl = tflags_sh;

    f32x4 Ot[4];
#pragma unroll
    for (int dt = 0; dt < 4; dt++) Ot[dt] = (f32x4){0.f, 0.f, 0.f, 0.f};
    f32x4 Osum = (f32x4){0.f, 0.f, 0.f, 0.f};   // denominator via ones-column MFMA
    float mrun = -1e30f;

    for (int t = 0; t < 32; ++t) {
        const int kt = t * 64;
        const size_t go = (size_t)kt * 3072;
        gl_lds16(kg0 + go, kl0);
        gl_lds16(kg1 + go, kl1);
        gl_lds16(vg0 + go, vl0);
        gl_lds16(vg1 + go, vl1);
        __syncthreads();

        // S^T tiles: z[tt] = K_tile(tt) x Q  -> lane holds z[key=tt*16+4g+j][q=r16]
        f32x4 z[4];
        __builtin_amdgcn_s_setprio(1);
#pragma unroll
        for (int tt = 0; tt < 4; tt++) {
            const int row = tt * 16 + r16;
            const int swz = row & 7;
            short8 a0 = *(const short8*)&Ks[row * 64 + ((g ^ swz) * 8)];
            short8 a1 = *(const short8*)&Ks[row * 64 + (((4 + g) ^ swz) * 8)];
            f32x4 zz = (f32x4){0.f, 0.f, 0.f, 0.f};
            zz = MFMA32(a0, qf0, zz);
            zz = MFMA32(a1, qf1, zz);
            z[tt] = zz;
        }
        __builtin_amdgcn_s_setprio(0);

        // row-max upper bound from raw z (mask bias <= 0, so zmax*SCALE >= true max;
        // over-estimate only rescales early — normalization stays exact)
        float m0 = max3f(z[0][0], z[0][1], z[0][2]);
        float m1 = max3f(z[0][3], z[1][0], z[1][1]);
        float m2 = max3f(z[1][2], z[1][3], z[2][0]);
        float m3 = max3f(z[2][1], z[2][2], z[2][3]);
        float m4 = max3f(z[3][0], z[3][1], z[3][2]);
        float zmax = fmaxf(max3f(m0, m1, m2), max3f(m3, m4, z[3][3]));
        zmax = fmaxf(zmax, __shfl_xor(zmax, 16));
        zmax = fmaxf(zmax, __shfl_xor(zmax, 32));
        float pmax = zmax * SCALE;

        // defer-max (THR = 11.5 in log2 domain ~= 8 nats)
        if (!__all(pmax - mrun <= 11.5f)) {
            float mnew = fmaxf(mrun, pmax);
            float alpha = exp2f(mrun - mnew);
            mrun = mnew;
            Osum *= alpha;
#pragma unroll
            for (int dt = 0; dt < 4; dt++) Ot[dt] *= alpha;
        }

        // p = 2^(z*SCALE + mb - mrun); fast path skips mb entirely
        s16x4 pb[4];
        const float negm = -mrun;
        if (__builtin_expect((tfl >> t) & 1u, 0)) {
            // masked tile (rare): bias from global mask
            const int* mrow = mask + baserow + kt;
#pragma unroll
            for (int tt = 0; tt < 4; tt++) {
                float p[4];
#pragma unroll
                for (int j = 0; j < 4; j++) {
                    float mbj = mrow[tt * 16 + g * 4 + j] ? MNEG : 0.0f;
                    p[j] = exp2f(__builtin_fmaf(z[tt][j], SCALE, mbj + negm));
                }
                unsigned lo, hi;
                asm("v_cvt_pk_bf16_f32 %0, %1, %2" : "=v"(lo) : "v"(p[0]), "v"(p[1]));
                asm("v_cvt_pk_bf16_f32 %0, %1, %2" : "=v"(hi) : "v"(p[2]), "v"(p[3]));
                uint2 u; u.x = lo; u.y = hi;
                pb[tt] = __builtin_bit_cast(s16x4, u);
            }
        } else {
#pragma unroll
            for (int tt = 0; tt < 4; tt++) {
                float p0 = exp2f(__builtin_fmaf(z[tt][0], SCALE, negm));
                float p1 = exp2f(__builtin_fmaf(z[tt][1], SCALE, negm));
                float p2 = exp2f(__builtin_fmaf(z[tt][2], SCALE, negm));
                float p3 = exp2f(__builtin_fmaf(z[tt][3], SCALE, negm));
                unsigned lo, hi;
                asm("v_cvt_pk_bf16_f32 %0, %1, %2" : "=v"(lo) : "v"(p0), "v"(p1));
                asm("v_cvt_pk_bf16_f32 %0, %1, %2" : "=v"(hi) : "v"(p2), "v"(p3));
                uint2 u; u.x = lo; u.y = hi;
                pb[tt] = __builtin_bit_cast(s16x4, u);
            }
        }

        // PV: O^T[dt] += V^T_frag(tt,dt) x P_frag(tt); Osum += 1^T x P_frag(tt)
        s16x4 vf[4][4];
#pragma unroll
        for (int tt = 0; tt < 4; tt++)
#pragma unroll
            for (int dt = 0; dt < 4; dt++)
                asm volatile("ds_read_b64_tr_b16 %0, %1"
                             : "=v"(vf[tt][dt])
                             : "v"(vaddr + (unsigned)((tt * 4 + dt) * 512)));
        asm volatile("s_waitcnt lgkmcnt(0)" ::: "memory");
        __builtin_amdgcn_sched_barrier(0);
        __builtin_amdgcn_s_setprio(1);
#pragma unroll
        for (int tt = 0; tt < 4; tt++) {
#pragma unroll
            for (int dt = 0; dt < 4; dt++) Ot[dt] = MFMA16(vf[tt][dt], pb[tt], Ot[dt]);
            Osum = MFMA16(ONES, pb[tt], Osum);
        }
        __builtin_amdgcn_s_setprio(0);
        __syncthreads();
    }

    const float rl = 1.0f / Osum[0];
    u16* cp = ctx + (baserow + q0 + wid * 16 + r16) * 1024 + h * 64 + g * 4;
#pragma unroll
    for (int dt = 0; dt < 4; dt++) {
        ushort4 o4;
        o4.x = f2b(Ot[dt][0] * rl);
        o4.y = f2b(Ot[dt][1] * rl);
        o4.z = f2b(Ot[dt][2] * rl);
        o4.w = f2b(Ot[dt][3] * rl);
        *(ushort4*)(cp + dt * 16) = o4;
    }
}

// ---------------- fused residual + layernorm (res optional) ----------------
__global__ __launch_bounds__(256) void ln_kernel(const float* __restrict__ a, const float* __restrict__ res,
                                                 const float* __restrict__ gamma, const float* __restrict__ beta,
                                                 float* __restrict__ outf, u16* __restrict__ outb) {
    const int row = blockIdx.x, tid = threadIdx.x;
    const size_t base = (size_t)row * 1024 + tid * 4;
    float4 va = *(const float4*)(a + base);
    float x0 = va.x, x1 = va.y, x2 = va.z, x3 = va.w;
    if (res) {
        float4 vr = *(const float4*)(res + base);
        x0 += vr.x; x1 += vr.y; x2 += vr.z; x3 += vr.w;
    }
    float s = x0 + x1 + x2 + x3;
    float ss = x0 * x0 + x1 * x1 + x2 * x2 + x3 * x3;
#pragma unroll
    for (int m = 1; m < 64; m <<= 1) { s += __shfl_xor(s, m, 64); ss += __shfl_xor(ss, m, 64); }
    __shared__ float red[8];
    if ((tid & 63) == 0) { red[tid >> 6] = s; red[4 + (tid >> 6)] = ss; }
    __syncthreads();
    s = red[0] + red[1] + red[2] + red[3];
    ss = red[4] + red[5] + red[6] + red[7];
    float mu = s * (1.0f / 1024.0f);
    float var = ss * (1.0f / 1024.0f) - mu * mu;
    float rstd = rsqrtf(var + 1e-5f);
    float4 g4 = *(const float4*)(gamma + tid * 4);
    float4 b4 = *(const float4*)(beta + tid * 4);
    float y0 = (x0 - mu) * rstd * g4.x + b4.x;
    float y1 = (x1 - mu) * rstd * g4.y + b4.y;
    float y2 = (x2 - mu) * rstd * g4.z + b4.z;
    float y3 = (x3 - mu) * rstd * g4.w + b4.w;
    *(float4*)(outf + base) = make_float4(y0, y1, y2, y3);
    if (outb) {
        ushort4 ob;
        ob.x = f2b(y0); ob.y = f2b(y1); ob.z = f2b(y2); ob.w = f2b(y3);
        *(ushort4*)(outb + base) = ob;
    }
}

extern "C" void kernel_launch(void* const* d_in, const int* in_sizes, int n_in, void* d_out, int out_size,
                              void* d_ws, size_t ws_size, hipStream_t stream) {
    const float* x = (const float*)d_in[0];
    const int* mask = (const int*)d_in[1];
    const float* Wq = (const float*)d_in[2];
    const float* bq = (const float*)d_in[3];
    const float* Wk = (const float*)d_in[4];
    const float* bk = (const float*)d_in[5];
    const float* Wv = (const float*)d_in[6];
    const float* bv = (const float*)d_in[7];
    const float* Wo = (const float*)d_in[8];
    const float* bo = (const float*)d_in[9];
    const float* ln1s = (const float*)d_in[10];
    const float* ln1b = (const float*)d_in[11];
    const float* W1 = (const float*)d_in[12];
    const float* b1 = (const float*)d_in[13];
    const float* W2 = (const float*)d_in[14];
    const float* b2 = (const float*)d_in[15];
    const float* ln2s = (const float*)d_in[16];
    const float* ln2b = (const float*)d_in[17];
    float* out = (float*)d_out;
    char* ws = (char*)d_ws;

    const size_t MB = 1024 * 1024;
    u16* XB = (u16*)(ws + 0);                 // x bf16 [8192][1024]
    u16* WTq = (u16*)(ws + 16 * MB);          // [Wq^T;Wk^T;Wv^T] = Bt[3072][1024]
    u16* WTk = WTq + 1024 * 1024;
    u16* WTv = WTk + 1024 * 1024;
    u16* WTo = WTv + 1024 * 1024;             // Wo^T [1024][1024]
    u16* WT1 = WTo + 1024 * 1024;             // W1^T [4096][1024]
    u16* WT2 = WT1 + 4096 * 1024;             // W2^T [1024][4096]
    float* BIAS = (float*)(ws + 40 * MB);
    u16* QKV = (u16*)(ws + 41 * MB);          // [8192][3072] bf16
    u16* CTX = (u16*)(ws + 0);                // [8192][1024] bf16 (reuse XB)
    float* ATT = (float*)(ws + 41 * MB);      // attn_out + x, fp32 (reuse QKV)
    float* Hbuf = (float*)(ws + 73 * MB);
    u16* HB = (u16*)(ws + 105 * MB);
    u16* MLP1 = (u16*)(ws + 121 * MB);        // [8192][4096] bf16
    float* MLP2 = (float*)(ws + 41 * MB);     // mlp2 + h, fp32 (reuse ATT)

    dim3 tb(32, 8);
    cast_bf16<<<8192, 256, 0, stream>>>(x, XB, 8192 * 1024);
    transpose_cast<<<dim3(32, 32), tb, 0, stream>>>(Wq, WTq, 1024, 1024);
    transpose_cast<<<dim3(32, 32), tb, 0, stream>>>(Wk, WTk, 1024, 1024);
    transpose_cast<<<dim3(32, 32), tb, 0, stream>>>(Wv, WTv, 1024, 1024);
    transpose_cast<<<dim3(32, 32), tb, 0, stream>>>(Wo, WTo, 1024, 1024);
    transpose_cast<<<dim3(128, 32), tb, 0, stream>>>(W1, WT1, 1024, 4096);
    transpose_cast<<<dim3(32, 128), tb, 0, stream>>>(W2, WT2, 4096, 1024);
    pack_bias<<<36, 256, 0, stream>>>(bq, bk, bv, bo, b1, b2, BIAS);

    // QKV projection: [8192][3072]
    gemm_bt<false, true, false><<<dim3(64, 24), 256, 0, stream>>>(XB, WTq, BIAS, nullptr, QKV, nullptr, 8192, 3072, 1024);
    attn_kernel<<<dim3(32, 16, 4), 256, 0, stream>>>(QKV, mask, CTX);
    // output projection + residual x (fp32 out)
    gemm_bt<false, false, true><<<dim3(64, 8), 256, 0, stream>>>(CTX, WTo, BIAS + 3072, ATT, nullptr, x, 8192, 1024, 1024);
    ln_kernel<<<8192, 256, 0, stream>>>(ATT, nullptr, ln1s, ln1b, Hbuf, HB);
    // mlp1 = gelu(h @ W1 + b1)
    gemm_bt<true, true, false><<<dim3(64, 32), 256, 0, stream>>>(HB, WT1, BIAS + 4096, nullptr, MLP1, nullptr, 8192, 4096, 1024);
    // mlp2 = mlp1 @ W2 + b2 + h
    gemm_bt<false, false, true><<<dim3(64, 8), 256, 0, stream>>>(MLP1, WT2, BIAS + 8192, MLP2, nullptr, Hbuf, 8192, 1024, 4096);
    ln_kernel<<<8192, 256, 0, stream>>>(MLP2, nullptr, ln2s, ln2b, out, nullptr);
}

// Round 10
// 518.276 us; speedup vs baseline: 1.0300x; 1.0022x over previous
//
#include <hip/hip_runtime.h>
#include <hip/hip_bf16.h>

typedef __attribute__((ext_vector_type(8))) short short8;
typedef __attribute__((ext_vector_type(4))) short s16x4;
typedef __attribute__((ext_vector_type(4))) float f32x4;
typedef unsigned short u16;

#define DEV __device__ __forceinline__
#define MFMA32(a, b, c) __builtin_amdgcn_mfma_f32_16x16x32_bf16(a, b, c, 0, 0, 0)
#define MFMA16(a, b, c) __builtin_amdgcn_mfma_f32_16x16x16bf16_1k(a, b, c, 0, 0, 0)

DEV u16 f2b(float f) {
    __hip_bfloat16 h = __float2bfloat16(f);
    return __builtin_bit_cast(unsigned short, h);
}

DEV float max3f(float a, float b, float c) {
    float d;
    asm("v_max3_f32 %0, %1, %2, %3" : "=v"(d) : "v"(a), "v"(b), "v"(c));
    return d;
}

DEV void gl_lds16(const u16* g, u16* l) {
    __builtin_amdgcn_global_load_lds((const unsigned int*)g, (unsigned int*)l, 16, 0, 0);
}

// ---------------- cast x: fp32 -> bf16 ----------------
__global__ __launch_bounds__(256) void cast_bf16(const float* __restrict__ in, u16* __restrict__ out, int n) {
    int i = (blockIdx.x * 256 + threadIdx.x) * 4;
    if (i < n) {
        float4 v = *(const float4*)(in + i);
        ushort4 o;
        o.x = f2b(v.x); o.y = f2b(v.y); o.z = f2b(v.z); o.w = f2b(v.w);
        *(ushort4*)(out + i) = o;
    }
}

// ---------------- transpose + cast: W[R][C] fp32 -> Wt[C][R] bf16 ----------------
__global__ __launch_bounds__(256) void transpose_cast(const float* __restrict__ in, u16* __restrict__ out,
                                                      int R, int C) {
    __shared__ float t[32][33];
    int bx = blockIdx.x * 32;
    int by = blockIdx.y * 32;
    int tx = threadIdx.x, ty = threadIdx.y;  // (32, 8)
#pragma unroll
    for (int i = 0; i < 32; i += 8) t[ty + i][tx] = in[(size_t)(by + ty + i) * C + bx + tx];
    __syncthreads();
#pragma unroll
    for (int i = 0; i < 32; i += 8) out[(size_t)(bx + ty + i) * R + by + tx] = f2b(t[tx][ty + i]);
}

// ---------------- pack biases into one buffer ----------------
__global__ __launch_bounds__(256) void pack_bias(const float* __restrict__ bq, const float* __restrict__ bk,
                                                 const float* __restrict__ bv, const float* __restrict__ bo,
                                                 const float* __restrict__ b1, const float* __restrict__ b2,
                                                 float* __restrict__ out) {
    int i = blockIdx.x * 256 + threadIdx.x;
    if (i >= 9216) return;
    float v;
    if (i < 1024) v = bq[i];
    else if (i < 2048) v = bk[i - 1024];
    else if (i < 3072) v = bv[i - 2048];
    else if (i < 4096) v = bo[i - 3072];
    else if (i < 8192) v = b1[i - 4096];
    else v = b2[i - 8192];
    out[i] = v;
}

// ---------------- GEMM: C[M][N] = A[M][K] * Bt[N][K]^T + bias (+res), optional GELU ----------------
// m97 structure (proven best here): 128x128 tile, BK=32, 256 threads (4 waves, 2x2),
// global_load_lds width 16, 2 barriers per K-step, ~3+ blocks/CU for implicit overlap.
template <bool GELU, bool BF16OUT, bool RESID>
__global__ __launch_bounds__(256) void gemm_bt(const u16* __restrict__ A, const u16* __restrict__ B,
                                               const float* __restrict__ bias, float* __restrict__ cf,
                                               u16* __restrict__ cb, const float* __restrict__ res,
                                               int M, int N, int K) {
    __shared__ __align__(16) u16 As[128 * 32];
    __shared__ __align__(16) u16 Bs[128 * 32];
    const int tid = threadIdx.x;
    const int wid = tid >> 6, lane = tid & 63;
    const int wr = wid >> 1, wc = wid & 1;
    const int m0 = blockIdx.x * 128, n0 = blockIdx.y * 128;
    const int r16 = lane & 15, g = lane >> 4;
    const int lrow = lane >> 2, lk = (lane & 3) * 8;

    f32x4 acc[4][4];
#pragma unroll
    for (int i = 0; i < 4; i++)
#pragma unroll
        for (int j = 0; j < 4; j++) acc[i][j] = (f32x4){0.f, 0.f, 0.f, 0.f};

    const u16* ga = A + (size_t)(m0 + wid * 32 + lrow) * K + lk;
    const u16* gb = B + (size_t)(n0 + wid * 32 + lrow) * K + lk;
    u16* lA0 = &As[(wid * 32) * 32];
    u16* lA1 = &As[(wid * 32 + 16) * 32];
    u16* lB0 = &Bs[(wid * 32) * 32];
    u16* lB1 = &Bs[(wid * 32 + 16) * 32];

    for (int kt = 0; kt < K; kt += 32) {
        gl_lds16(ga + kt, lA0);
        gl_lds16(ga + (size_t)16 * K + kt, lA1);
        gl_lds16(gb + kt, lB0);
        gl_lds16(gb + (size_t)16 * K + kt, lB1);
        __syncthreads();
        short8 af[4], bfr[4];
#pragma unroll
        for (int i = 0; i < 4; i++) af[i] = *(const short8*)&As[(wr * 64 + i * 16 + r16) * 32 + g * 8];
#pragma unroll
        for (int j = 0; j < 4; j++) bfr[j] = *(const short8*)&Bs[(wc * 64 + j * 16 + r16) * 32 + g * 8];
#pragma unroll
        for (int i = 0; i < 4; i++)
#pragma unroll
            for (int j = 0; j < 4; j++) acc[i][j] = MFMA32(af[i], bfr[j], acc[i][j]);
        __syncthreads();
    }

#pragma unroll
    for (int i = 0; i < 4; i++) {
#pragma unroll
        for (int j = 0; j < 4; j++) {
#pragma unroll
            for (int r = 0; r < 4; r++) {
                int row = m0 + wr * 64 + i * 16 + g * 4 + r;
                int col = n0 + wc * 64 + j * 16 + r16;
                float v = acc[i][j][r] + bias[col];
                if (RESID) v += res[(size_t)row * N + col];
                if (GELU) v = 0.5f * v * (1.0f + erff(v * 0.70710678118654752f));
                if (BF16OUT) cb[(size_t)row * N + col] = f2b(v);
                else cf[(size_t)row * N + col] = v;
            }
        }
    }
}

// ---------------- flash attention (swapped-QK^T, KBLK=64, 2 q-groups/wave) ----------------
// Block = 4 waves, 128 q-rows; wave wid owns rows q0+wid*32 .. +32 as two groups A/B of 16.
// K/V tiles shared across groups: K-frag reads and V tr-reads amortize 2x; two independent
// softmax chains per wave fill the dependency gaps. PV pipelined per-tt (lgkmcnt(4)).
__global__ __launch_bounds__(256, 4) void attn_kernel(const u16* __restrict__ qkv, const int* __restrict__ mask,
                                                      u16* __restrict__ ctx) {
    const int tid = threadIdx.x, wid = tid >> 6, lane = tid & 63;
    const int r16 = lane & 15, g = lane >> 4;
    const int h = blockIdx.y, b = blockIdx.z;
    const size_t baserow = (size_t)b * 2048;
    const int q0 = blockIdx.x * 128;

    __shared__ __align__(16) u16 Ks[64 * 64];
    __shared__ __align__(16) u16 Vs[64 * 64];
    __shared__ unsigned tflags_sh;

    const float SCALE = 0.18033688011112042f;   // 0.125 * log2(e)
    const float MNEG = -6.196328018e9f;         // -2^32 * log2(e)
    const s16x4 ONES = {(short)0x3F80, (short)0x3F80, (short)0x3F80, (short)0x3F80};

    short8 qfA0, qfA1, qfB0, qfB1;
    {
        const u16* qp = qkv + (baserow + q0 + wid * 32 + r16) * 3072 + h * 64 + g * 8;
        qfA0 = *(const short8*)qp;
        qfA1 = *(const short8*)(qp + 32);
        qfB0 = *(const short8*)(qp + (size_t)16 * 3072);
        qfB1 = *(const short8*)(qp + (size_t)16 * 3072 + 32);
    }

    // per-tile has-mask bitmask (one u32 for all 32 tiles), computed once
    if (tid == 0) tflags_sh = 0;
    __syncthreads();
    for (int r = 0; r < 8; ++r) {
        int v = mask[baserow + r * 256 + tid];
        unsigned long long bal = __ballot(v != 0);
        if (bal != 0 && lane == 0) atomicOr(&tflags_sh, 1u << (r * 4 + wid));
    }

    const int L = lane;
    const u16* kg0 = qkv + (baserow + wid * 16 + (L >> 3)) * 3072 + 1024 + h * 64 + ((L & 7) ^ (L >> 3)) * 8;
    const u16* kg1 = kg0 + (size_t)8 * 3072;
    u16* kl0 = &Ks[wid * 1024];
    u16* kl1 = &Ks[wid * 1024 + 512];
    const u16* vg0 = qkv + (baserow + wid * 16 + ((L & 31) >> 1)) * 3072 + 2048 + h * 64
                     + ((L >> 5) * 16 + (L & 1) * 8);
    const u16* vg1 = vg0 + 32;
    u16* vl0 = &Vs[wid * 1024];
    u16* vl1 = &Vs[wid * 1024 + 512];
    const unsigned vaddr = (unsigned)(unsigned long long)&Vs[0] + (unsigned)(r16 * 2 + g * 128);

    __syncthreads();            // tflags ready
    const unsigned tfl = tflags_sh;

    f32x4 OtA[4], OtB[4];
#pragma unroll
    for (int dt = 0; dt < 4; dt++) { OtA[dt] = (f32x4){0.f, 0.f, 0.f, 0.f}; OtB[dt] = (f32x4){0.f, 0.f, 0.f, 0.f}; }
    f32x4 OsumA = (f32x4){0.f, 0.f, 0.f, 0.f}, OsumB = (f32x4){0.f, 0.f, 0.f, 0.f};
    float mrunA = -1e30f, mrunB = -1e30f;

    for (int t = 0; t < 32; ++t) {
        const int kt = t * 64;
        const size_t go = (size_t)kt * 3072;
        gl_lds16(kg0 + go, kl0);
        gl_lds16(kg1 + go, kl1);
        gl_lds16(vg0 + go, vl0);
        gl_lds16(vg1 + go, vl1);
        __syncthreads();

        // S^T tiles for both q-groups (K fragments shared)
        f32x4 zA[4], zB[4];
        __builtin_amdgcn_s_setprio(1);
#pragma unroll
        for (int tt = 0; tt < 4; tt++) {
            const int row = tt * 16 + r16;
            const int swz = row & 7;
            short8 a0 = *(const short8*)&Ks[row * 64 + ((g ^ swz) * 8)];
            short8 a1 = *(const short8*)&Ks[row * 64 + (((4 + g) ^ swz) * 8)];
            f32x4 za = (f32x4){0.f, 0.f, 0.f, 0.f};
            za = MFMA32(a0, qfA0, za);
            za = MFMA32(a1, qfA1, za);
            zA[tt] = za;
            f32x4 zb = (f32x4){0.f, 0.f, 0.f, 0.f};
            zb = MFMA32(a0, qfB0, zb);
            zb = MFMA32(a1, qfB1, zb);
            zB[tt] = zb;
        }
        __builtin_amdgcn_s_setprio(0);

        // row-max upper bound from raw z (mask bias <= 0 -> early rescale only)
        float a0_ = max3f(zA[0][0], zA[0][1], zA[0][2]);
        float a1_ = max3f(zA[0][3], zA[1][0], zA[1][1]);
        float a2_ = max3f(zA[1][2], zA[1][3], zA[2][0]);
        float a3_ = max3f(zA[2][1], zA[2][2], zA[2][3]);
        float a4_ = max3f(zA[3][0], zA[3][1], zA[3][2]);
        float zmaxA = fmaxf(max3f(a0_, a1_, a2_), max3f(a3_, a4_, zA[3][3]));
        float b0_ = max3f(zB[0][0], zB[0][1], zB[0][2]);
        float b1_ = max3f(zB[0][3], zB[1][0], zB[1][1]);
        float b2_ = max3f(zB[1][2], zB[1][3], zB[2][0]);
        float b3_ = max3f(zB[2][1], zB[2][2], zB[2][3]);
        float b4_ = max3f(zB[3][0], zB[3][1], zB[3][2]);
        float zmaxB = fmaxf(max3f(b0_, b1_, b2_), max3f(b3_, b4_, zB[3][3]));
        zmaxA = fmaxf(zmaxA, __shfl_xor(zmaxA, 16));
        zmaxB = fmaxf(zmaxB, __shfl_xor(zmaxB, 16));
        zmaxA = fmaxf(zmaxA, __shfl_xor(zmaxA, 32));
        zmaxB = fmaxf(zmaxB, __shfl_xor(zmaxB, 32));
        float pmaxA = zmaxA * SCALE, pmaxB = zmaxB * SCALE;

        // defer-max (THR = 11.5 in log2 domain ~= 8 nats), per group
        if (!__all(pmaxA - mrunA <= 11.5f)) {
            float mnew = fmaxf(mrunA, pmaxA);
            float alpha = exp2f(mrunA - mnew);
            mrunA = mnew;
            OsumA *= alpha;
#pragma unroll
            for (int dt = 0; dt < 4; dt++) OtA[dt] *= alpha;
        }
        if (!__all(pmaxB - mrunB <= 11.5f)) {
            float mnew = fmaxf(mrunB, pmaxB);
            float alpha = exp2f(mrunB - mnew);
            mrunB = mnew;
            OsumB *= alpha;
#pragma unroll
            for (int dt = 0; dt < 4; dt++) OtB[dt] *= alpha;
        }

        // p = 2^(z*SCALE + mb - mrun); fast path skips mb
        s16x4 pbA[4], pbB[4];
        const float negmA = -mrunA, negmB = -mrunB;
        if (__builtin_expect((tfl >> t) & 1u, 0)) {
            const int* mrow = mask + baserow + kt;
#pragma unroll
            for (int tt = 0; tt < 4; tt++) {
                float pa[4], pbv[4];
#pragma unroll
                for (int j = 0; j < 4; j++) {
                    float mbj = mrow[tt * 16 + g * 4 + j] ? MNEG : 0.0f;
                    pa[j] = exp2f(__builtin_fmaf(zA[tt][j], SCALE, mbj + negmA));
                    pbv[j] = exp2f(__builtin_fmaf(zB[tt][j], SCALE, mbj + negmB));
                }
                unsigned lo, hi;
                asm("v_cvt_pk_bf16_f32 %0, %1, %2" : "=v"(lo) : "v"(pa[0]), "v"(pa[1]));
                asm("v_cvt_pk_bf16_f32 %0, %1, %2" : "=v"(hi) : "v"(pa[2]), "v"(pa[3]));
                uint2 ua; ua.x = lo; ua.y = hi;
                pbA[tt] = __builtin_bit_cast(s16x4, ua);
                asm("v_cvt_pk_bf16_f32 %0, %1, %2" : "=v"(lo) : "v"(pbv[0]), "v"(pbv[1]));
                asm("v_cvt_pk_bf16_f32 %0, %1, %2" : "=v"(hi) : "v"(pbv[2]), "v"(pbv[3]));
                uint2 ub; ub.x = lo; ub.y = hi;
                pbB[tt] = __builtin_bit_cast(s16x4, ub);
            }
        } else {
#pragma unroll
            for (int tt = 0; tt < 4; tt++) {
                float pa0 = exp2f(__builtin_fmaf(zA[tt][0], SCALE, negmA));
                float pa1 = exp2f(__builtin_fmaf(zA[tt][1], SCALE, negmA));
                float pa2 = exp2f(__builtin_fmaf(zA[tt][2], SCALE, negmA));
                float pa3 = exp2f(__builtin_fmaf(zA[tt][3], SCALE, negmA));
                float pb0 = exp2f(__builtin_fmaf(zB[tt][0], SCALE, negmB));
                float pb1 = exp2f(__builtin_fmaf(zB[tt][1], SCALE, negmB));
                float pb2 = exp2f(__builtin_fmaf(zB[tt][2], SCALE, negmB));
                float pb3 = exp2f(__builtin_fmaf(zB[tt][3], SCALE, negmB));
                unsigned lo, hi;
                asm("v_cvt_pk_bf16_f32 %0, %1, %2" : "=v"(lo) : "v"(pa0), "v"(pa1));
                asm("v_cvt_pk_bf16_f32 %0, %1, %2" : "=v"(hi) : "v"(pa2), "v"(pa3));
                uint2 ua; ua.x = lo; ua.y = hi;
                pbA[tt] = __builtin_bit_cast(s16x4, ua);
                asm("v_cvt_pk_bf16_f32 %0, %1, %2" : "=v"(lo) : "v"(pb0), "v"(pb1));
                asm("v_cvt_pk_bf16_f32 %0, %1, %2" : "=v"(hi) : "v"(pb2), "v"(pb3));
                uint2 ub; ub.x = lo; ub.y = hi;
                pbB[tt] = __builtin_bit_cast(s16x4, ub);
            }
        }

        // PV, pipelined per key-subtile: tr_read(tt+1) in flight while MFMA(tt) runs
        s16x4 vf[2][4];
#pragma unroll
        for (int dt = 0; dt < 4; dt++)
            asm volatile("ds_read_b64_tr_b16 %0, %1"
                         : "=v"(vf[0][dt]) : "v"(vaddr + (unsigned)(dt * 512)));
#pragma unroll
        for (int tt = 0; tt < 4; tt++) {
            if (tt < 3) {
#pragma unroll
                for (int dt = 0; dt < 4; dt++)
                    asm volatile("ds_read_b64_tr_b16 %0, %1"
                                 : "=v"(vf[(tt + 1) & 1][dt])
                                 : "v"(vaddr + (unsigned)(((tt + 1) * 4 + dt) * 512)));
                asm volatile("s_waitcnt lgkmcnt(4)" ::: "memory");
            } else {
                asm volatile("s_waitcnt lgkmcnt(0)" ::: "memory");
            }
            __builtin_amdgcn_sched_barrier(0);
            __builtin_amdgcn_s_setprio(1);
#pragma unroll
            for (int dt = 0; dt < 4; dt++) {
                OtA[dt] = MFMA16(vf[tt & 1][dt], pbA[tt], OtA[dt]);
                OtB[dt] = MFMA16(vf[tt & 1][dt], pbB[tt], OtB[dt]);
            }
            OsumA = MFMA16(ONES, pbA[tt], OsumA);
            OsumB = MFMA16(ONES, pbB[tt], OsumB);
            __builtin_amdgcn_s_setprio(0);
        }
        __syncthreads();
    }

    const float rlA = 1.0f / OsumA[0];
    const float rlB = 1.0f / OsumB[0];
    u16* cpA = ctx + (baserow + q0 + wid * 32 + r16) * 1024 + h * 64 + g * 4;
    u16* cpB = cpA + (size_t)16 * 1024;
#pragma unroll
    for (int dt = 0; dt < 4; dt++) {
        ushort4 oa, ob;
        oa.x = f2b(OtA[dt][0] * rlA); oa.y = f2b(OtA[dt][1] * rlA);
        oa.z = f2b(OtA[dt][2] * rlA); oa.w = f2b(OtA[dt][3] * rlA);
        ob.x = f2b(OtB[dt][0] * rlB); ob.y = f2b(OtB[dt][1] * rlB);
        ob.z = f2b(OtB[dt][2] * rlB); ob.w = f2b(OtB[dt][3] * rlB);
        *(ushort4*)(cpA + dt * 16) = oa;
        *(ushort4*)(cpB + dt * 16) = ob;
    }
}

// ---------------- fused residual + layernorm (res optional) ----------------
__global__ __launch_bounds__(256) void ln_kernel(const float* __restrict__ a, const float* __restrict__ res,
                                                 const float* __restrict__ gamma, const float* __restrict__ beta,
                                                 float* __restrict__ outf, u16* __restrict__ outb) {
    const int row = blockIdx.x, tid = threadIdx.x;
    const size_t base = (size_t)row * 1024 + tid * 4;
    float4 va = *(const float4*)(a + base);
    float x0 = va.x, x1 = va.y, x2 = va.z, x3 = va.w;
    if (res) {
        float4 vr = *(const float4*)(res + base);
        x0 += vr.x; x1 += vr.y; x2 += vr.z; x3 += vr.w;
    }
    float s = x0 + x1 + x2 + x3;
    float ss = x0 * x0 + x1 * x1 + x2 * x2 + x3 * x3;
#pragma unroll
    for (int m = 1; m < 64; m <<= 1) { s += __shfl_xor(s, m, 64); ss += __shfl_xor(ss, m, 64); }
    __shared__ float red[8];
    if ((tid & 63) == 0) { red[tid >> 6] = s; red[4 + (tid >> 6)] = ss; }
    __syncthreads();
    s = red[0] + red[1] + red[2] + red[3];
    ss = red[4] + red[5] + red[6] + red[7];
    float mu = s * (1.0f / 1024.0f);
    float var = ss * (1.0f / 1024.0f) - mu * mu;
    float rstd = rsqrtf(var + 1e-5f);
    float4 g4 = *(const float4*)(gamma + tid * 4);
    float4 b4 = *(const float4*)(beta + tid * 4);
    float y0 = (x0 - mu) * rstd * g4.x + b4.x;
    float y1 = (x1 - mu) * rstd * g4.y + b4.y;
    float y2 = (x2 - mu) * rstd * g4.z + b4.z;
    float y3 = (x3 - mu) * rstd * g4.w + b4.w;
    *(float4*)(outf + base) = make_float4(y0, y1, y2, y3);
    if (outb) {
        ushort4 ob;
        ob.x = f2b(y0); ob.y = f2b(y1); ob.z = f2b(y2); ob.w = f2b(y3);
        *(ushort4*)(outb + base) = ob;
    }
}

extern "C" void kernel_launch(void* const* d_in, const int* in_sizes, int n_in, void* d_out, int out_size,
                              void* d_ws, size_t ws_size, hipStream_t stream) {
    const float* x = (const float*)d_in[0];
    const int* mask = (const int*)d_in[1];
    const float* Wq = (const float*)d_in[2];
    const float* bq = (const float*)d_in[3];
    const float* Wk = (const float*)d_in[4];
    const float* bk = (const float*)d_in[5];
    const float* Wv = (const float*)d_in[6];
    const float* bv = (const float*)d_in[7];
    const float* Wo = (const float*)d_in[8];
    const float* bo = (const float*)d_in[9];
    const float* ln1s = (const float*)d_in[10];
    const float* ln1b = (const float*)d_in[11];
    const float* W1 = (const float*)d_in[12];
    const float* b1 = (const float*)d_in[13];
    const float* W2 = (const float*)d_in[14];
    const float* b2 = (const float*)d_in[15];
    const float* ln2s = (const float*)d_in[16];
    const float* ln2b = (const float*)d_in[17];
    float* out = (float*)d_out;
    char* ws = (char*)d_ws;

    const size_t MB = 1024 * 1024;
    u16* XB = (u16*)(ws + 0);                 // x bf16 [8192][1024]
    u16* WTq = (u16*)(ws + 16 * MB);          // [Wq^T;Wk^T;Wv^T] = Bt[3072][1024]
    u16* WTk = WTq + 1024 * 1024;
    u16* WTv = WTk + 1024 * 1024;
    u16* WTo = WTv + 1024 * 1024;             // Wo^T [1024][1024]
    u16* WT1 = WTo + 1024 * 1024;             // W1^T [4096][1024]
    u16* WT2 = WT1 + 4096 * 1024;             // W2^T [1024][4096]
    float* BIAS = (float*)(ws + 40 * MB);
    u16* QKV = (u16*)(ws + 41 * MB);          // [8192][3072] bf16
    u16* CTX = (u16*)(ws + 0);                // [8192][1024] bf16 (reuse XB)
    float* ATT = (float*)(ws + 41 * MB);      // attn_out + x, fp32 (reuse QKV)
    float* Hbuf = (float*)(ws + 73 * MB);
    u16* HB = (u16*)(ws + 105 * MB);
    u16* MLP1 = (u16*)(ws + 121 * MB);        // [8192][4096] bf16
    float* MLP2 = (float*)(ws + 41 * MB);     // mlp2 + h, fp32 (reuse ATT)

    dim3 tb(32, 8);
    cast_bf16<<<8192, 256, 0, stream>>>(x, XB, 8192 * 1024);
    transpose_cast<<<dim3(32, 32), tb, 0, stream>>>(Wq, WTq, 1024, 1024);
    transpose_cast<<<dim3(32, 32), tb, 0, stream>>>(Wk, WTk, 1024, 1024);
    transpose_cast<<<dim3(32, 32), tb, 0, stream>>>(Wv, WTv, 1024, 1024);
    transpose_cast<<<dim3(32, 32), tb, 0, stream>>>(Wo, WTo, 1024, 1024);
    transpose_cast<<<dim3(128, 32), tb, 0, stream>>>(W1, WT1, 1024, 4096);
    transpose_cast<<<dim3(32, 128), tb, 0, stream>>>(W2, WT2, 4096, 1024);
    pack_bias<<<36, 256, 0, stream>>>(bq, bk, bv, bo, b1, b2, BIAS);

    // QKV projection: [8192][3072]
    gemm_bt<false, true, false><<<dim3(64, 24), 256, 0, stream>>>(XB, WTq, BIAS, nullptr, QKV, nullptr, 8192, 3072, 1024);
    attn_kernel<<<dim3(16, 16, 4), 256, 0, stream>>>(QKV, mask, CTX);
    // output projection + residual x (fp32 out)
    gemm_bt<false, false, true><<<dim3(64, 8), 256, 0, stream>>>(CTX, WTo, BIAS + 3072, ATT, nullptr, x, 8192, 1024, 1024);
    ln_kernel<<<8192, 256, 0, stream>>>(ATT, nullptr, ln1s, ln1b, Hbuf, HB);
    // mlp1 = gelu(h @ W1 + b1)
    gemm_bt<true, true, false><<<dim3(64, 32), 256, 0, stream>>>(HB, WT1, BIAS + 4096, nullptr, MLP1, nullptr, 8192, 4096, 1024);
    // mlp2 = mlp1 @ W2 + b2 + h
    gemm_bt<false, false, true><<<dim3(64, 8), 256, 0, stream>>>(MLP1, WT2, BIAS + 8192, MLP2, nullptr, Hbuf, 8192, 1024, 4096);
    ln_kernel<<<8192, 256, 0, stream>>>(MLP2, nullptr, ln2s, ln2b, out, nullptr);
}

// Round 11
// 486.101 us; speedup vs baseline: 1.0981x; 1.0662x over previous
//
#include <hip/hip_runtime.h>
#include <hip/hip_bf16.h>

typedef __attribute__((ext_vector_type(8))) short short8;
typedef __attribute__((ext_vector_type(4))) short s16x4;
typedef __attribute__((ext_vector_type(4))) float f32x4;
typedef unsigned short u16;

#define DEV __device__ __forceinline__
#define MFMA32(a, b, c) __builtin_amdgcn_mfma_f32_16x16x32_bf16(a, b, c, 0, 0, 0)
#define MFMA16(a, b, c) __builtin_amdgcn_mfma_f32_16x16x16bf16_1k(a, b, c, 0, 0, 0)

DEV u16 f2b(float f) {
    __hip_bfloat16 h = __float2bfloat16(f);
    return __builtin_bit_cast(unsigned short, h);
}

DEV float max3f(float a, float b, float c) {
    float d;
    asm("v_max3_f32 %0, %1, %2, %3" : "=v"(d) : "v"(a), "v"(b), "v"(c));
    return d;
}

DEV void gl_lds16(const u16* g, u16* l) {
    __builtin_amdgcn_global_load_lds((const unsigned int*)g, (unsigned int*)l, 16, 0, 0);
}

// ---------------- cast x: fp32 -> bf16 ----------------
__global__ __launch_bounds__(256) void cast_bf16(const float* __restrict__ in, u16* __restrict__ out, int n) {
    int i = (blockIdx.x * 256 + threadIdx.x) * 4;
    if (i < n) {
        float4 v = *(const float4*)(in + i);
        ushort4 o;
        o.x = f2b(v.x); o.y = f2b(v.y); o.z = f2b(v.z); o.w = f2b(v.w);
        *(ushort4*)(out + i) = o;
    }
}

// ---------------- transpose + cast: W[R][C] fp32 -> Wt[C][R] bf16 ----------------
__global__ __launch_bounds__(256) void transpose_cast(const float* __restrict__ in, u16* __restrict__ out,
                                                      int R, int C) {
    __shared__ float t[32][33];
    int bx = blockIdx.x * 32;
    int by = blockIdx.y * 32;
    int tx = threadIdx.x, ty = threadIdx.y;  // (32, 8)
#pragma unroll
    for (int i = 0; i < 32; i += 8) t[ty + i][tx] = in[(size_t)(by + ty + i) * C + bx + tx];
    __syncthreads();
#pragma unroll
    for (int i = 0; i < 32; i += 8) out[(size_t)(bx + ty + i) * R + by + tx] = f2b(t[tx][ty + i]);
}

// ---------------- pack biases into one buffer ----------------
__global__ __launch_bounds__(256) void pack_bias(const float* __restrict__ bq, const float* __restrict__ bk,
                                                 const float* __restrict__ bv, const float* __restrict__ bo,
                                                 const float* __restrict__ b1, const float* __restrict__ b2,
                                                 float* __restrict__ out) {
    int i = blockIdx.x * 256 + threadIdx.x;
    if (i >= 9216) return;
    float v;
    if (i < 1024) v = bq[i];
    else if (i < 2048) v = bk[i - 1024];
    else if (i < 3072) v = bv[i - 2048];
    else if (i < 4096) v = bo[i - 3072];
    else if (i < 8192) v = b1[i - 4096];
    else v = b2[i - 8192];
    out[i] = v;
}

// ---------------- GEMM: C[M][N] = A[M][K] * Bt[N][K]^T + bias (+res), optional GELU ----------------
// m97 2-barrier structure, BK=64: 128x128 tile, 256 threads (4 waves, 2x2), 32 KiB LDS,
// G4 XOR swizzle both-sides (LDS chunk c of row r holds global chunk c^(r&7)) since rows
// are 128 B. Halves barrier/vmcnt-drain count vs BK=32; accumulation order identical.
template <bool GELU, bool BF16OUT, bool RESID>
__global__ __launch_bounds__(256) void gemm_bt(const u16* __restrict__ A, const u16* __restrict__ B,
                                               const float* __restrict__ bias, float* __restrict__ cf,
                                               u16* __restrict__ cb, const float* __restrict__ res,
                                               int M, int N, int K) {
    __shared__ __align__(16) u16 As[128 * 64];
    __shared__ __align__(16) u16 Bs[128 * 64];
    const int tid = threadIdx.x;
    const int wid = tid >> 6, lane = tid & 63;
    const int wr = wid >> 1, wc = wid & 1;
    const int m0 = blockIdx.x * 128, n0 = blockIdx.y * 128;
    const int r16 = lane & 15, g = lane >> 4;
    const int sw = r16 & 7;

    f32x4 acc[4][4];
#pragma unroll
    for (int i = 0; i < 4; i++)
#pragma unroll
        for (int j = 0; j < 4; j++) acc[i][j] = (f32x4){0.f, 0.f, 0.f, 0.f};

    // staging: thread tid covers (row = tid>>3 (+32j), chunk = tid&7); source inverse-swizzled
    const int srow = tid >> 3;
    const int schunk = (tid & 7) ^ (srow & 7);
    const u16* ga = A + (size_t)(m0 + srow) * K + schunk * 8;
    const u16* gb = B + (size_t)(n0 + srow) * K + schunk * 8;

    for (int kt = 0; kt < K; kt += 64) {
#pragma unroll
        for (int j = 0; j < 4; j++) {
            gl_lds16(ga + (size_t)(j * 32) * K + kt, &As[(j * 32 + wid * 8) * 64]);
            gl_lds16(gb + (size_t)(j * 32) * K + kt, &Bs[(j * 32 + wid * 8) * 64]);
        }
        __syncthreads();
#pragma unroll
        for (int ks = 0; ks < 2; ks++) {
            short8 af[4], bfr[4];
#pragma unroll
            for (int i = 0; i < 4; i++) {
                int row = wr * 64 + i * 16 + r16;
                af[i] = *(const short8*)((const char*)As + row * 128 + (((ks * 4 + g) ^ sw) * 16));
            }
#pragma unroll
            for (int j = 0; j < 4; j++) {
                int row = wc * 64 + j * 16 + r16;
                bfr[j] = *(const short8*)((const char*)Bs + row * 128 + (((ks * 4 + g) ^ sw) * 16));
            }
#pragma unroll
            for (int i = 0; i < 4; i++)
#pragma unroll
                for (int j = 0; j < 4; j++) acc[i][j] = MFMA32(af[i], bfr[j], acc[i][j]);
        }
        __syncthreads();
    }

#pragma unroll
    for (int i = 0; i < 4; i++) {
#pragma unroll
        for (int j = 0; j < 4; j++) {
#pragma unroll
            for (int r = 0; r < 4; r++) {
                int row = m0 + wr * 64 + i * 16 + g * 4 + r;
                int col = n0 + wc * 64 + j * 16 + r16;
                float v = acc[i][j][r] + bias[col];
                if (RESID) v += res[(size_t)row * N + col];
                if (GELU) v = 0.5f * v * (1.0f + erff(v * 0.70710678118654752f));
                if (BF16OUT) cb[(size_t)row * N + col] = f2b(v);
                else cf[(size_t)row * N + col] = v;
            }
        }
    }
}

// ---------------- flash attention (swapped-QK^T, KBLK=64, 2 q-groups/wave) ----------------
__global__ __launch_bounds__(256, 4) void attn_kernel(const u16* __restrict__ qkv, const int* __restrict__ mask,
                                                      u16* __restrict__ ctx) {
    const int tid = threadIdx.x, wid = tid >> 6, lane = tid & 63;
    const int r16 = lane & 15, g = lane >> 4;
    const int h = blockIdx.y, b = blockIdx.z;
    const size_t baserow = (size_t)b * 2048;
    const int q0 = blockIdx.x * 128;

    __shared__ __align__(16) u16 Ks[64 * 64];
    __shared__ __align__(16) u16 Vs[64 * 64];
    __shared__ unsigned tflags_sh;

    const float SCALE = 0.18033688011112042f;   // 0.125 * log2(e)
    const float MNEG = -6.196328018e9f;         // -2^32 * log2(e)
    const s16x4 ONES = {(short)0x3F80, (short)0x3F80, (short)0x3F80, (short)0x3F80};

    short8 qfA0, qfA1, qfB0, qfB1;
    {
        const u16* qp = qkv + (baserow + q0 + wid * 32 + r16) * 3072 + h * 64 + g * 8;
        qfA0 = *(const short8*)qp;
        qfA1 = *(const short8*)(qp + 32);
        qfB0 = *(const short8*)(qp + (size_t)16 * 3072);
        qfB1 = *(const short8*)(qp + (size_t)16 * 3072 + 32);
    }

    // per-tile has-mask bitmask (one u32 for all 32 tiles), computed once
    if (tid == 0) tflags_sh = 0;
    __syncthreads();
    for (int r = 0; r < 8; ++r) {
        int v = mask[baserow + r * 256 + tid];
        unsigned long long bal = __ballot(v != 0);
        if (bal != 0 && lane == 0) atomicOr(&tflags_sh, 1u << (r * 4 + wid));
    }

    const int L = lane;
    const u16* kg0 = qkv + (baserow + wid * 16 + (L >> 3)) * 3072 + 1024 + h * 64 + ((L & 7) ^ (L >> 3)) * 8;
    const u16* kg1 = kg0 + (size_t)8 * 3072;
    u16* kl0 = &Ks[wid * 1024];
    u16* kl1 = &Ks[wid * 1024 + 512];
    const u16* vg0 = qkv + (baserow + wid * 16 + ((L & 31) >> 1)) * 3072 + 2048 + h * 64
                     + ((L >> 5) * 16 + (L & 1) * 8);
    const u16* vg1 = vg0 + 32;
    u16* vl0 = &Vs[wid * 1024];
    u16* vl1 = &Vs[wid * 1024 + 512];
    const unsigned vaddr = (unsigned)(unsigned long long)&Vs[0] + (unsigned)(r16 * 2 + g * 128);

    __syncthreads();            // tflags ready
    const unsigned tfl = tflags_sh;

    f32x4 OtA[4], OtB[4];
#pragma unroll
    for (int dt = 0; dt < 4; dt++) { OtA[dt] = (f32x4){0.f, 0.f, 0.f, 0.f}; OtB[dt] = (f32x4){0.f, 0.f, 0.f, 0.f}; }
    f32x4 OsumA = (f32x4){0.f, 0.f, 0.f, 0.f}, OsumB = (f32x4){0.f, 0.f, 0.f, 0.f};
    float mrunA = -1e30f, mrunB = -1e30f;

    for (int t = 0; t < 32; ++t) {
        const int kt = t * 64;
        const size_t go = (size_t)kt * 3072;
        gl_lds16(kg0 + go, kl0);
        gl_lds16(kg1 + go, kl1);
        gl_lds16(vg0 + go, vl0);
        gl_lds16(vg1 + go, vl1);
        __syncthreads();

        // S^T tiles for both q-groups (K fragments shared)
        f32x4 zA[4], zB[4];
        __builtin_amdgcn_s_setprio(1);
#pragma unroll
        for (int tt = 0; tt < 4; tt++) {
            const int row = tt * 16 + r16;
            const int swz = row & 7;
            short8 a0 = *(const short8*)&Ks[row * 64 + ((g ^ swz) * 8)];
            short8 a1 = *(const short8*)&Ks[row * 64 + (((4 + g) ^ swz) * 8)];
            f32x4 za = (f32x4){0.f, 0.f, 0.f, 0.f};
            za = MFMA32(a0, qfA0, za);
            za = MFMA32(a1, qfA1, za);
            zA[tt] = za;
            f32x4 zb = (f32x4){0.f, 0.f, 0.f, 0.f};
            zb = MFMA32(a0, qfB0, zb);
            zb = MFMA32(a1, qfB1, zb);
            zB[tt] = zb;
        }
        __builtin_amdgcn_s_setprio(0);

        // row-max upper bound from raw z (mask bias <= 0 -> early rescale only)
        float a0_ = max3f(zA[0][0], zA[0][1], zA[0][2]);
        float a1_ = max3f(zA[0][3], zA[1][0], zA[1][1]);
        float a2_ = max3f(zA[1][2], zA[1][3], zA[2][0]);
        float a3_ = max3f(zA[2][1], zA[2][2], zA[2][3]);
        float a4_ = max3f(zA[3][0], zA[3][1], zA[3][2]);
        float zmaxA = fmaxf(max3f(a0_, a1_, a2_), max3f(a3_, a4_, zA[3][3]));
        float b0_ = max3f(zB[0][0], zB[0][1], zB[0][2]);
        float b1_ = max3f(zB[0][3], zB[1][0], zB[1][1]);
        float b2_ = max3f(zB[1][2], zB[1][3], zB[2][0]);
        float b3_ = max3f(zB[2][1], zB[2][2], zB[2][3]);
        float b4_ = max3f(zB[3][0], zB[3][1], zB[3][2]);
        float zmaxB = fmaxf(max3f(b0_, b1_, b2_), max3f(b3_, b4_, zB[3][3]));
        zmaxA = fmaxf(zmaxA, __shfl_xor(zmaxA, 16));
        zmaxB = fmaxf(zmaxB, __shfl_xor(zmaxB, 16));
        zmaxA = fmaxf(zmaxA, __shfl_xor(zmaxA, 32));
        zmaxB = fmaxf(zmaxB, __shfl_xor(zmaxB, 32));
        float pmaxA = zmaxA * SCALE, pmaxB = zmaxB * SCALE;

        // defer-max (THR = 11.5 in log2 domain ~= 8 nats), per group
        if (!__all(pmaxA - mrunA <= 11.5f)) {
            float mnew = fmaxf(mrunA, pmaxA);
            float alpha = exp2f(mrunA - mnew);
            mrunA = mnew;
            OsumA *= alpha;
#pragma unroll
            for (int dt = 0; dt < 4; dt++) OtA[dt] *= alpha;
        }
        if (!__all(pmaxB - mrunB <= 11.5f)) {
            float mnew = fmaxf(mrunB, pmaxB);
            float alpha = exp2f(mrunB - mnew);
            mrunB = mnew;
            OsumB *= alpha;
#pragma unroll
            for (int dt = 0; dt < 4; dt++) OtB[dt] *= alpha;
        }

        // p = 2^(z*SCALE + mb - mrun); fast path skips mb
        s16x4 pbA[4], pbB[4];
        const float negmA = -mrunA, negmB = -mrunB;
        if (__builtin_expect((tfl >> t) & 1u, 0)) {
            const int* mrow = mask + baserow + kt;
#pragma unroll
            for (int tt = 0; tt < 4; tt++) {
                float pa[4], pbv[4];
#pragma unroll
                for (int j = 0; j < 4; j++) {
                    float mbj = mrow[tt * 16 + g * 4 + j] ? MNEG : 0.0f;
                    pa[j] = exp2f(__builtin_fmaf(zA[tt][j], SCALE, mbj + negmA));
                    pbv[j] = exp2f(__builtin_fmaf(zB[tt][j], SCALE, mbj + negmB));
                }
                unsigned lo, hi;
                asm("v_cvt_pk_bf16_f32 %0, %1, %2" : "=v"(lo) : "v"(pa[0]), "v"(pa[1]));
                asm("v_cvt_pk_bf16_f32 %0, %1, %2" : "=v"(hi) : "v"(pa[2]), "v"(pa[3]));
                uint2 ua; ua.x = lo; ua.y = hi;
                pbA[tt] = __builtin_bit_cast(s16x4, ua);
                asm("v_cvt_pk_bf16_f32 %0, %1, %2" : "=v"(lo) : "v"(pbv[0]), "v"(pbv[1]));
                asm("v_cvt_pk_bf16_f32 %0, %1, %2" : "=v"(hi) : "v"(pbv[2]), "v"(pbv[3]));
                uint2 ub; ub.x = lo; ub.y = hi;
                pbB[tt] = __builtin_bit_cast(s16x4, ub);
            }
        } else {
#pragma unroll
            for (int tt = 0; tt < 4; tt++) {
                float pa0 = exp2f(__builtin_fmaf(zA[tt][0], SCALE, negmA));
                float pa1 = exp2f(__builtin_fmaf(zA[tt][1], SCALE, negmA));
                float pa2 = exp2f(__builtin_fmaf(zA[tt][2], SCALE, negmA));
                float pa3 = exp2f(__builtin_fmaf(zA[tt][3], SCALE, negmA));
                float pb0 = exp2f(__builtin_fmaf(zB[tt][0], SCALE, negmB));
                float pb1 = exp2f(__builtin_fmaf(zB[tt][1], SCALE, negmB));
                float pb2 = exp2f(__builtin_fmaf(zB[tt][2], SCALE, negmB));
                float pb3 = exp2f(__builtin_fmaf(zB[tt][3], SCALE, negmB));
                unsigned lo, hi;
                asm("v_cvt_pk_bf16_f32 %0, %1, %2" : "=v"(lo) : "v"(pa0), "v"(pa1));
                asm("v_cvt_pk_bf16_f32 %0, %1, %2" : "=v"(hi) : "v"(pa2), "v"(pa3));
                uint2 ua; ua.x = lo; ua.y = hi;
                pbA[tt] = __builtin_bit_cast(s16x4, ua);
                asm("v_cvt_pk_bf16_f32 %0, %1, %2" : "=v"(lo) : "v"(pb0), "v"(pb1));
                asm("v_cvt_pk_bf16_f32 %0, %1, %2" : "=v"(hi) : "v"(pb2), "v"(pb3));
                uint2 ub; ub.x = lo; ub.y = hi;
                pbB[tt] = __builtin_bit_cast(s16x4, ub);
            }
        }

        // PV, pipelined per key-subtile: tr_read(tt+1) in flight while MFMA(tt) runs
        s16x4 vf[2][4];
#pragma unroll
        for (int dt = 0; dt < 4; dt++)
            asm volatile("ds_read_b64_tr_b16 %0, %1"
                         : "=v"(vf[0][dt]) : "v"(vaddr + (unsigned)(dt * 512)));
#pragma unroll
        for (int tt = 0; tt < 4; tt++) {
            if (tt < 3) {
#pragma unroll
                for (int dt = 0; dt < 4; dt++)
                    asm volatile("ds_read_b64_tr_b16 %0, %1"
                                 : "=v"(vf[(tt + 1) & 1][dt])
                                 : "v"(vaddr + (unsigned)(((tt + 1) * 4 + dt) * 512)));
                asm volatile("s_waitcnt lgkmcnt(4)" ::: "memory");
            } else {
                asm volatile("s_waitcnt lgkmcnt(0)" ::: "memory");
            }
            __builtin_amdgcn_sched_barrier(0);
            __builtin_amdgcn_s_setprio(1);
#pragma unroll
            for (int dt = 0; dt < 4; dt++) {
                OtA[dt] = MFMA16(vf[tt & 1][dt], pbA[tt], OtA[dt]);
                OtB[dt] = MFMA16(vf[tt & 1][dt], pbB[tt], OtB[dt]);
            }
            OsumA = MFMA16(ONES, pbA[tt], OsumA);
            OsumB = MFMA16(ONES, pbB[tt], OsumB);
            __builtin_amdgcn_s_setprio(0);
        }
        __syncthreads();
    }

    const float rlA = 1.0f / OsumA[0];
    const float rlB = 1.0f / OsumB[0];
    u16* cpA = ctx + (baserow + q0 + wid * 32 + r16) * 1024 + h * 64 + g * 4;
    u16* cpB = cpA + (size_t)16 * 1024;
#pragma unroll
    for (int dt = 0; dt < 4; dt++) {
        ushort4 oa, ob;
        oa.x = f2b(OtA[dt][0] * rlA); oa.y = f2b(OtA[dt][1] * rlA);
        oa.z = f2b(OtA[dt][2] * rlA); oa.w = f2b(OtA[dt][3] * rlA);
        ob.x = f2b(OtB[dt][0] * rlB); ob.y = f2b(OtB[dt][1] * rlB);
        ob.z = f2b(OtB[dt][2] * rlB); ob.w = f2b(OtB[dt][3] * rlB);
        *(ushort4*)(cpA + dt * 16) = oa;
        *(ushort4*)(cpB + dt * 16) = ob;
    }
}

// ---------------- fused residual + layernorm (res optional) ----------------
__global__ __launch_bounds__(256) void ln_kernel(const float* __restrict__ a, const float* __restrict__ res,
                                                 const float* __restrict__ gamma, const float* __restrict__ beta,
                                                 float* __restrict__ outf, u16* __restrict__ outb) {
    const int row = blockIdx.x, tid = threadIdx.x;
    const size_t base = (size_t)row * 1024 + tid * 4;
    float4 va = *(const float4*)(a + base);
    float x0 = va.x, x1 = va.y, x2 = va.z, x3 = va.w;
    if (res) {
        float4 vr = *(const float4*)(res + base);
        x0 += vr.x; x1 += vr.y; x2 += vr.z; x3 += vr.w;
    }
    float s = x0 + x1 + x2 + x3;
    float ss = x0 * x0 + x1 * x1 + x2 * x2 + x3 * x3;
#pragma unroll
    for (int m = 1; m < 64; m <<= 1) { s += __shfl_xor(s, m, 64); ss += __shfl_xor(ss, m, 64); }
    __shared__ float red[8];
    if ((tid & 63) == 0) { red[tid >> 6] = s; red[4 + (tid >> 6)] = ss; }
    __syncthreads();
    s = red[0] + red[1] + red[2] + red[3];
    ss = red[4] + red[5] + red[6] + red[7];
    float mu = s * (1.0f / 1024.0f);
    float var = ss * (1.0f / 1024.0f) - mu * mu;
    float rstd = rsqrtf(var + 1e-5f);
    float4 g4 = *(const float4*)(gamma + tid * 4);
    float4 b4 = *(const float4*)(beta + tid * 4);
    float y0 = (x0 - mu) * rstd * g4.x + b4.x;
    float y1 = (x1 - mu) * rstd * g4.y + b4.y;
    float y2 = (x2 - mu) * rstd * g4.z + b4.z;
    float y3 = (x3 - mu) * rstd * g4.w + b4.w;
    *(float4*)(outf + base) = make_float4(y0, y1, y2, y3);
    if (outb) {
        ushort4 ob;
        ob.x = f2b(y0); ob.y = f2b(y1); ob.z = f2b(y2); ob.w = f2b(y3);
        *(ushort4*)(outb + base) = ob;
    }
}

extern "C" void kernel_launch(void* const* d_in, const int* in_sizes, int n_in, void* d_out, int out_size,
                              void* d_ws, size_t ws_size, hipStream_t stream) {
    const float* x = (const float*)d_in[0];
    const int* mask = (const int*)d_in[1];
    const float* Wq = (const float*)d_in[2];
    const float* bq = (const float*)d_in[3];
    const float* Wk = (const float*)d_in[4];
    const float* bk = (const float*)d_in[5];
    const float* Wv = (const float*)d_in[6];
    const float* bv = (const float*)d_in[7];
    const float* Wo = (const float*)d_in[8];
    const float* bo = (const float*)d_in[9];
    const float* ln1s = (const float*)d_in[10];
    const float* ln1b = (const float*)d_in[11];
    const float* W1 = (const float*)d_in[12];
    const float* b1 = (const float*)d_in[13];
    const float* W2 = (const float*)d_in[14];
    const float* b2 = (const float*)d_in[15];
    const float* ln2s = (const float*)d_in[16];
    const float* ln2b = (const float*)d_in[17];
    float* out = (float*)d_out;
    char* ws = (char*)d_ws;

    const size_t MB = 1024 * 1024;
    u16* XB = (u16*)(ws + 0);                 // x bf16 [8192][1024]
    u16* WTq = (u16*)(ws + 16 * MB);          // [Wq^T;Wk^T;Wv^T] = Bt[3072][1024]
    u16* WTk = WTq + 1024 * 1024;
    u16* WTv = WTk + 1024 * 1024;
    u16* WTo = WTv + 1024 * 1024;             // Wo^T [1024][1024]
    u16* WT1 = WTo + 1024 * 1024;             // W1^T [4096][1024]
    u16* WT2 = WT1 + 4096 * 1024;             // W2^T [1024][4096]
    float* BIAS = (float*)(ws + 40 * MB);
    u16* QKV = (u16*)(ws + 41 * MB);          // [8192][3072] bf16
    u16* CTX = (u16*)(ws + 0);                // [8192][1024] bf16 (reuse XB)
    float* ATT = (float*)(ws + 41 * MB);      // attn_out + x, fp32 (reuse QKV)
    float* Hbuf = (float*)(ws + 73 * MB);
    u16* HB = (u16*)(ws + 105 * MB);
    u16* MLP1 = (u16*)(ws + 121 * MB);        // [8192][4096] bf16
    float* MLP2 = (float*)(ws + 41 * MB);     // mlp2 + h, fp32 (reuse ATT)

    dim3 tb(32, 8);
    cast_bf16<<<8192, 256, 0, stream>>>(x, XB, 8192 * 1024);
    transpose_cast<<<dim3(32, 32), tb, 0, stream>>>(Wq, WTq, 1024, 1024);
    transpose_cast<<<dim3(32, 32), tb, 0, stream>>>(Wk, WTk, 1024, 1024);
    transpose_cast<<<dim3(32, 32), tb, 0, stream>>>(Wv, WTv, 1024, 1024);
    transpose_cast<<<dim3(32, 32), tb, 0, stream>>>(Wo, WTo, 1024, 1024);
    transpose_cast<<<dim3(128, 32), tb, 0, stream>>>(W1, WT1, 1024, 4096);
    transpose_cast<<<dim3(32, 128), tb, 0, stream>>>(W2, WT2, 4096, 1024);
    pack_bias<<<36, 256, 0, stream>>>(bq, bk, bv, bo, b1, b2, BIAS);

    // QKV projection: [8192][3072]
    gemm_bt<false, true, false><<<dim3(64, 24), 256, 0, stream>>>(XB, WTq, BIAS, nullptr, QKV, nullptr, 8192, 3072, 1024);
    attn_kernel<<<dim3(16, 16, 4), 256, 0, stream>>>(QKV, mask, CTX);
    // output projection + residual x (fp32 out)
    gemm_bt<false, false, true><<<dim3(64, 8), 256, 0, stream>>>(CTX, WTo, BIAS + 3072, ATT, nullptr, x, 8192, 1024, 1024);
    ln_kernel<<<8192, 256, 0, stream>>>(ATT, nullptr, ln1s, ln1b, Hbuf, HB);
    // mlp1 = gelu(h @ W1 + b1)
    gemm_bt<true, true, false><<<dim3(64, 32), 256, 0, stream>>>(HB, WT1, BIAS + 4096, nullptr, MLP1, nullptr, 8192, 4096, 1024);
    // mlp2 = mlp1 @ W2 + b2 + h
    gemm_bt<false, false, true><<<dim3(64, 8), 256, 0, stream>>>(MLP1, WT2, BIAS + 8192, MLP2, nullptr, Hbuf, 8192, 1024, 4096);
    ln_kernel<<<8192, 256, 0, stream>>>(MLP2, nullptr, ln2s, ln2b, out, nullptr);
}